// Round 1
// baseline (309.198 us; speedup 1.0000x reference)
//
#include <hip/hip_runtime.h>

#define SEQ    2048
#define DMODEL 1024
#define NHEAD  16
#define DHEAD  64
#define NBATCH 2

typedef __bf16 bf16x8 __attribute__((ext_vector_type(8)));
typedef float f32x16 __attribute__((ext_vector_type(16)));
typedef unsigned short ushort8v __attribute__((ext_vector_type(8)));
typedef unsigned short ushort4v __attribute__((ext_vector_type(4)));
typedef int int4v __attribute__((ext_vector_type(4)));

static __device__ __forceinline__ unsigned short f2b(float f){
  unsigned int u = __builtin_bit_cast(unsigned int, f);
  u += 0x7fffu + ((u>>16)&1u);            // RNE to bf16
  return (unsigned short)(u>>16);
}
static __device__ __forceinline__ float b2f(unsigned short h){
  unsigned int u = ((unsigned int)h)<<16;
  return __builtin_bit_cast(float, u);
}
static __device__ __forceinline__ unsigned int pk2(float lo, float hi){
  return (unsigned int)f2b(lo) | ((unsigned int)f2b(hi)<<16);
}
static __device__ __forceinline__ f32x16 mfma32(bf16x8 a, bf16x8 b, f32x16 c){
  return __builtin_amdgcn_mfma_f32_32x32x16_bf16(a,b,c,0,0,0);
}

// ---------- A transpose + convert: At[q][k] = bf16(A[k][q]) ----------
__global__ __launch_bounds__(256) void cvtA(const float* __restrict__ A,
                                            unsigned short* __restrict__ At){
  __shared__ float T[64][65];
  const int tid = threadIdx.x;
  const int rb = blockIdx.y*64;   // k rows of A
  const int cb = blockIdx.x*64;   // q cols of A
  const int r = tid>>2, c0 = (tid&3)*16;
  const float* ap = A + (size_t)(rb+r)*SEQ + cb + c0;
  #pragma unroll
  for (int i=0;i<4;i++){
    float4 f = *(const float4*)(ap + 4*i);
    T[r][c0+4*i+0] = f.x; T[r][c0+4*i+1] = f.y;
    T[r][c0+4*i+2] = f.z; T[r][c0+4*i+3] = f.w;
  }
  __syncthreads();
  unsigned short tmp[16];
  #pragma unroll
  for (int j=0;j<16;j++) tmp[j] = f2b(T[c0+j][r]);
  ushort8v w0, w1;
  #pragma unroll
  for (int j=0;j<8;j++){ w0[j] = tmp[j]; w1[j] = tmp[8+j]; }
  unsigned short* dst = At + (size_t)(cb + r)*SEQ + rb + c0;
  *(ushort8v*)dst = w0;
  *(ushort8v*)(dst+8) = w1;
}

// ---------- fused q/k/v projection: Y = (X*W^T + b)*alpha, head layout ----------
__global__ __launch_bounds__(256) void proj_qkv(
    const float* __restrict__ qx, const float* __restrict__ kx, const float* __restrict__ vx,
    const float* __restrict__ Wq, const float* __restrict__ Wk, const float* __restrict__ Wv,
    const float* __restrict__ bq, const float* __restrict__ bk, const float* __restrict__ bv,
    unsigned short* __restrict__ qh, unsigned short* __restrict__ kh, unsigned short* __restrict__ vh)
{
  const int z = blockIdx.z;
  const float* X    = (z==0)? qx : (z==1)? kx : vx;
  const float* W    = (z==0)? Wq : (z==1)? Wk : Wv;
  const float* bias = (z==0)? bq : (z==1)? bk : bv;
  unsigned short* Y = (z==0)? qh : (z==1)? kh : vh;
  const float alpha = (z==0)? 0.125f : 1.0f;   // fold 1/sqrt(DK) into qh

  const int mb = blockIdx.y*128, nb = blockIdx.x*128;
  __shared__ unsigned short Xs[128][72];
  __shared__ unsigned short Ws[128][72];
  const int tid = threadIdx.x;
  const int lane = tid&63, wave = tid>>6;
  const int wr = wave>>1, wc = wave&1, l31 = lane&31, hi = lane>>5;
  f32x16 acc[2][2] = {};
  const int sr = tid>>1, sh = (tid&1)*32;

  for (int kb=0; kb<DMODEL; kb+=64){
    const float* xrow = X + (size_t)(mb+sr)*DMODEL + kb + sh;
    const float* wrow = W + (size_t)(nb+sr)*DMODEL + kb + sh;
    #pragma unroll
    for (int c=0;c<4;c++){
      float4 a0 = *(const float4*)(xrow + 8*c);
      float4 a1 = *(const float4*)(xrow + 8*c + 4);
      int4v px; px.x = pk2(a0.x,a0.y); px.y = pk2(a0.z,a0.w);
                px.z = pk2(a1.x,a1.y); px.w = pk2(a1.z,a1.w);
      *(int4v*)&Xs[sr][sh + 8*c] = px;
      float4 b0 = *(const float4*)(wrow + 8*c);
      float4 b1 = *(const float4*)(wrow + 8*c + 4);
      int4v pw; pw.x = pk2(b0.x,b0.y); pw.y = pk2(b0.z,b0.w);
                pw.z = pk2(b1.x,b1.y); pw.w = pk2(b1.z,b1.w);
      *(int4v*)&Ws[sr][sh + 8*c] = pw;
    }
    __syncthreads();
    #pragma unroll
    for (int s=0;s<4;s++){
      bf16x8 a0 = *(const bf16x8*)&Xs[64*wr +      l31][16*s + 8*hi];
      bf16x8 a1 = *(const bf16x8*)&Xs[64*wr + 32 + l31][16*s + 8*hi];
      bf16x8 b0 = *(const bf16x8*)&Ws[64*wc +      l31][16*s + 8*hi];
      bf16x8 b1 = *(const bf16x8*)&Ws[64*wc + 32 + l31][16*s + 8*hi];
      acc[0][0] = mfma32(a0,b0,acc[0][0]);
      acc[0][1] = mfma32(a0,b1,acc[0][1]);
      acc[1][0] = mfma32(a1,b0,acc[1][0]);
      acc[1][1] = mfma32(a1,b1,acc[1][1]);
    }
    __syncthreads();
  }
  #pragma unroll
  for (int fj=0; fj<2; fj++){
    const int e = nb + 64*wc + 32*fj + l31;
    const float bv_ = bias[e];
    const int hh = e>>6, dk = e&63;
    #pragma unroll
    for (int fi=0; fi<2; fi++){
      #pragma unroll
      for (int r=0;r<16;r++){
        const int i = mb + 64*wr + 32*fi + (r&3) + 8*(r>>2) + 4*hi;
        const int bb = i>>11, ss = i&(SEQ-1);
        Y[((size_t)((bb*NHEAD + hh)*SEQ + ss))*DHEAD + dk] = f2b((acc[fi][fj][r] + bv_)*alpha);
      }
    }
  }
}

// ---------- fused masked attention per (b,h,q-tile): x = (Qh Kh^T ∘ A^T) Vh ----------
__global__ __launch_bounds__(256) void attn(
    const unsigned short* __restrict__ qh, const unsigned short* __restrict__ kh,
    const unsigned short* __restrict__ vh, const unsigned short* __restrict__ At,
    unsigned short* __restrict__ xbuf)
{
  const int qblk = blockIdx.x;     // 0..15
  const int bh   = blockIdx.y;     // 0..31
  const int tid = threadIdx.x;
  const int lane = tid&63, wave = tid>>6;   // 4 waves, 32 q-rows each
  const int l31 = lane&31, hi = lane>>5;
  const size_t hb = (size_t)bh * SEQ * DHEAD;
  __shared__ unsigned short Vt[64][72];     // V^T tile: [d][k]

  const int qrow = qblk*128 + wave*32 + l31;
  const unsigned short* qp = qh + hb + (size_t)qrow*DHEAD;
  bf16x8 Qf[4];
  #pragma unroll
  for (int t=0;t<4;t++) Qf[t] = *(const bf16x8*)(qp + 16*t + 8*hi);

  f32x16 xacc[2] = {};

  const int vr = tid&63;            // k row (per lane)
  const int vd = (tid>>6)*16;       // d base (uniform per wave -> conflict-free writes)
  const unsigned short* arow = At + (size_t)qrow*SEQ;

  for (int kt=0; kt<32; kt++){
    const int kb = kt*64;
    __syncthreads();                 // prev PV reads done before Vt overwrite
    {
      const unsigned short* vp = vh + hb + (size_t)(kb + vr)*DHEAD + vd;
      ushort8v v0 = *(const ushort8v*)vp;
      ushort8v v1 = *(const ushort8v*)(vp + 8);
      #pragma unroll
      for (int j=0;j<8;j++){
        Vt[vd + j][vr]     = v0[j];
        Vt[vd + 8 + j][vr] = v1[j];
      }
    }
    // scores^T = K * Q^T (scale pre-folded into qh)
    f32x16 sacc[2] = {};
    const unsigned short* kp = kh + hb + (size_t)(kb + l31)*DHEAD;
    #pragma unroll
    for (int s=0;s<4;s++){
      bf16x8 k0 = *(const bf16x8*)(kp + 16*s + 8*hi);
      bf16x8 k1 = *(const bf16x8*)(kp + (size_t)32*DHEAD + 16*s + 8*hi);
      sacc[0] = mfma32(k0, Qf[s], sacc[0]);
      sacc[1] = mfma32(k1, Qf[s], sacc[1]);
    }
    // mask multiply (P^T[k][q] *= A[k][q]) + pack to bf16 pairs along k
    unsigned int wv[2][4], xv[2][4], pwv[2][4], pxv[2][4];
    #pragma unroll
    for (int fi=0; fi<2; fi++){
      #pragma unroll
      for (int mm=0; mm<4; mm++){
        ushort4v a4 = *(const ushort4v*)(arow + kb + 32*fi + 8*mm + 4*hi);
        const int rb2 = 4*mm;
        float p0 = sacc[fi][rb2+0]*b2f(a4[0]);
        float p1 = sacc[fi][rb2+1]*b2f(a4[1]);
        float p2 = sacc[fi][rb2+2]*b2f(a4[2]);
        float p3 = sacc[fi][rb2+3]*b2f(a4[3]);
        wv[fi][mm] = pk2(p0,p1);
        xv[fi][mm] = pk2(p2,p3);
      }
    }
    #pragma unroll
    for (int fi=0; fi<2; fi++){
      #pragma unroll
      for (int mm=0; mm<4; mm++){
        pwv[fi][mm] = __shfl_xor((unsigned int)wv[fi][mm], 32, 64);
        pxv[fi][mm] = __shfl_xor((unsigned int)xv[fi][mm], 32, 64);
      }
    }
    __syncthreads();                 // Vt staged
    // x += P * V   (P A-operand assembled in-register; row q = l31 matches sacc col)
    #pragma unroll
    for (int s2=0; s2<4; s2++){
      const int fi = s2>>1, sl = s2&1;
      int4v av;
      av.x = (int)(hi ? pwv[fi][2*sl+1] : wv[fi][2*sl]);
      av.y = (int)(hi ? pxv[fi][2*sl+1] : xv[fi][2*sl]);
      av.z = (int)(hi ? wv[fi][2*sl+1]  : pwv[fi][2*sl]);
      av.w = (int)(hi ? xv[fi][2*sl+1]  : pxv[fi][2*sl]);
      bf16x8 pa = __builtin_bit_cast(bf16x8, av);
      bf16x8 vb0 = *(const bf16x8*)&Vt[     l31][16*s2 + 8*hi];
      bf16x8 vb1 = *(const bf16x8*)&Vt[32 + l31][16*s2 + 8*hi];
      xacc[0] = mfma32(pa, vb0, xacc[0]);
      xacc[1] = mfma32(pa, vb1, xacc[1]);
    }
  }
  const int b = bh>>4, h = bh&15;
  #pragma unroll
  for (int fj=0; fj<2; fj++){
    #pragma unroll
    for (int r=0;r<16;r++){
      const int qq = qblk*128 + wave*32 + (r&3) + 8*(r>>2) + 4*hi;
      const int dd = 32*fj + l31;
      xbuf[((size_t)(b*SEQ + qq))*DMODEL + h*DHEAD + dd] = f2b(xacc[fj][r]);
    }
  }
}

// ---------- output projection: out = x * Wo^T + bo (fp32 out) ----------
__global__ __launch_bounds__(256) void oproj(
    const unsigned short* __restrict__ xb, const float* __restrict__ Wo,
    const float* __restrict__ bo, float* __restrict__ out)
{
  const int mb = blockIdx.y*128, nb = blockIdx.x*128;
  __shared__ unsigned short Xs[128][72];
  __shared__ unsigned short Ws[128][72];
  const int tid = threadIdx.x;
  const int lane = tid&63, wave = tid>>6;
  const int wr = wave>>1, wc = wave&1, l31 = lane&31, hi = lane>>5;
  f32x16 acc[2][2] = {};
  const int sr = tid>>1, sh = (tid&1)*32;
  for (int kb=0; kb<DMODEL; kb+=64){
    const unsigned short* xrow = xb + (size_t)(mb+sr)*DMODEL + kb + sh;
    const float* wrow = Wo + (size_t)(nb+sr)*DMODEL + kb + sh;
    #pragma unroll
    for (int c=0;c<4;c++){
      *(ushort8v*)&Xs[sr][sh + 8*c] = *(const ushort8v*)(xrow + 8*c);
      float4 b0 = *(const float4*)(wrow + 8*c);
      float4 b1 = *(const float4*)(wrow + 8*c + 4);
      int4v pw; pw.x = pk2(b0.x,b0.y); pw.y = pk2(b0.z,b0.w);
                pw.z = pk2(b1.x,b1.y); pw.w = pk2(b1.z,b1.w);
      *(int4v*)&Ws[sr][sh + 8*c] = pw;
    }
    __syncthreads();
    #pragma unroll
    for (int s=0;s<4;s++){
      bf16x8 a0 = *(const bf16x8*)&Xs[64*wr +      l31][16*s + 8*hi];
      bf16x8 a1 = *(const bf16x8*)&Xs[64*wr + 32 + l31][16*s + 8*hi];
      bf16x8 b0 = *(const bf16x8*)&Ws[64*wc +      l31][16*s + 8*hi];
      bf16x8 b1 = *(const bf16x8*)&Ws[64*wc + 32 + l31][16*s + 8*hi];
      acc[0][0] = mfma32(a0,b0,acc[0][0]);
      acc[0][1] = mfma32(a0,b1,acc[0][1]);
      acc[1][0] = mfma32(a1,b0,acc[1][0]);
      acc[1][1] = mfma32(a1,b1,acc[1][1]);
    }
    __syncthreads();
  }
  #pragma unroll
  for (int fj=0; fj<2; fj++){
    const int e = nb + 64*wc + 32*fj + l31;
    const float bv_ = bo[e];
    #pragma unroll
    for (int fi=0; fi<2; fi++){
      #pragma unroll
      for (int r=0;r<16;r++){
        const int i = mb + 64*wr + 32*fi + (r&3) + 8*(r>>2) + 4*hi;
        out[(size_t)i*DMODEL + e] = acc[fi][fj][r] + bv_;
      }
    }
  }
}

extern "C" void kernel_launch(void* const* d_in, const int* in_sizes, int n_in,
                              void* d_out, int out_size, void* d_ws, size_t ws_size,
                              hipStream_t stream)
{
  const float* q  = (const float*)d_in[0];
  const float* k  = (const float*)d_in[1];
  const float* v  = (const float*)d_in[2];
  const float* A  = (const float*)d_in[3];
  const float* Wq = (const float*)d_in[4];
  const float* bq = (const float*)d_in[5];
  const float* Wk = (const float*)d_in[6];
  const float* bk = (const float*)d_in[7];
  const float* Wv = (const float*)d_in[8];
  const float* bv = (const float*)d_in[9];
  const float* Wo = (const float*)d_in[10];
  const float* bo = (const float*)d_in[11];
  float* out = (float*)d_out;

  // workspace layout (bf16 elements): qh, kh, vh, x, A^T  -> 5 * 8MB = 40MB
  unsigned short* ws = (unsigned short*)d_ws;
  const size_t NE = (size_t)NBATCH*SEQ*DMODEL;   // 4M elements
  unsigned short* qh = ws;
  unsigned short* kh = qh + NE;
  unsigned short* vh = kh + NE;
  unsigned short* xb = vh + NE;
  unsigned short* At = xb + NE;

  cvtA<<<dim3(SEQ/64, SEQ/64), 256, 0, stream>>>(A, At);
  proj_qkv<<<dim3(DMODEL/128, (NBATCH*SEQ)/128, 3), 256, 0, stream>>>(
      q,k,v, Wq,Wk,Wv, bq,bk,bv, qh,kh,vh);
  attn<<<dim3(SEQ/128, NBATCH*NHEAD), 256, 0, stream>>>(qh, kh, vh, At, xb);
  oproj<<<dim3(DMODEL/128, (NBATCH*SEQ)/128), 256, 0, stream>>>(xb, Wo, bo, out);
}